// Round 1
// baseline (234.148 us; speedup 1.0000x reference)
//
#include <hip/hip_runtime.h>

#define NN 14
#define EE 182

typedef __attribute__((ext_vector_type(8))) short bf16x8;
typedef __attribute__((ext_vector_type(4))) short bf16x4;
typedef __attribute__((ext_vector_type(4))) float f32x4;
typedef __attribute__((ext_vector_type(4))) unsigned u32x4;
typedef __attribute__((ext_vector_type(2))) unsigned u32x2;

__device__ __forceinline__ unsigned f2bf(float f) {            // RNE (prep only)
    unsigned u = __float_as_uint(f);
    return (u + 0x7fffu + ((u >> 16) & 1u)) >> 16;
}
// pack two f32 -> bf16 pair (round-half-away): add,add,v_perm = 3 VALU
__device__ __forceinline__ unsigned pack2bf(float lo, float hi) {
    return __builtin_amdgcn_perm(__float_as_uint(hi) + 0x8000u,
                                 __float_as_uint(lo) + 0x8000u, 0x07060302u);
}
__device__ __forceinline__ bf16x8 mk8(unsigned a, unsigned b, unsigned c, unsigned d) {
    u32x4 u = {a, b, c, d};
    return __builtin_bit_cast(bf16x8, u);
}
__device__ __forceinline__ bf16x4 mk4(unsigned a, unsigned b) {
    u32x2 u = {a, b};
    return __builtin_bit_cast(bf16x4, u);
}

// ---------------------------------------------------------------------------
// Weight pre-pack (every launch; d_ws re-poisoned each call). Unchanged.
// ---------------------------------------------------------------------------
__global__ void prep_pack(const float* __restrict__ W1, const float* __restrict__ W2,
                          const float* __restrict__ Wl, const float* __restrict__ Wpred,
                          const float* __restrict__ bl, const float* __restrict__ bp,
                          const float* __restrict__ as1, const float* __restrict__ ad1,
                          const float* __restrict__ as2, const float* __restrict__ ad2,
                          short* __restrict__ wp1, short* __restrict__ wp2,
                          short* __restrict__ battn1, short* __restrict__ battn2,
                          float* __restrict__ wcombP) {
    int gid = blockIdx.x * 256 + threadIdx.x;
    if (gid < 32768) {
        int j = gid & 7, L = (gid >> 3) & 63, kk = (gid >> 9) & 3, nt = gid >> 11;
        int k = kk * 32 + (L >> 4) * 8 + j, n = nt * 16 + (L & 15);
        wp1[gid] = (short)f2bf(W1[k * 256 + n]);
    } else if (gid < 49152) {
        int g2 = gid - 32768;
        int j = g2 & 7, L = (g2 >> 3) & 63, kk = (g2 >> 9) & 1, nt = g2 >> 10;
        int k = kk * 32 + (L >> 4) * 8 + j, n = nt * 16 + (L & 15);
        wp2[g2] = (short)f2bf(W2[k * 256 + n]);
    } else if (gid < 51200) {
        int g2 = gid - 49152;                 // (kk*64+L)*8+j, kk<4
        int j = g2 & 7, L = (g2 >> 3) & 63, kk = g2 >> 9;
        int n = L & 15, k = kk * 32 + (L >> 4) * 8 + j;
        float val = 0.f;
        if (n < 8) {
            const float* av = ((n >> 2) ? ad1 : as1) + (n & 3) * 64;
            const float* wr = W1 + k * 256 + (n & 3) * 64;
            for (int c = 0; c < 64; ++c) val += wr[c] * av[c];
        }
        battn1[g2] = (short)f2bf(val);
    } else if (gid < 52224) {
        int g2 = gid - 51200;                 // kk<2
        int j = g2 & 7, L = (g2 >> 3) & 63, kk = g2 >> 9;
        int n = L & 15, k = kk * 32 + (L >> 4) * 8 + j;
        float val = 0.f;
        if (n < 8) {
            const float* av = ((n >> 2) ? ad2 : as2) + (n & 3) * 64;
            const float* wr = W2 + k * 256 + (n & 3) * 64;
            for (int c = 0; c < 64; ++c) val += wr[c] * av[c];
        }
        battn2[g2] = (short)f2bf(val);
    } else if (gid < 56320) {
        int o = gid - 52224;                  // ((ct*4+q)*16+m)*4+r
        int r = o & 3, i4 = o >> 2;
        int m = i4 & 15, ctq = i4 >> 4;
        int q = ctq & 3, ct = ctq >> 2;
        int chan = ct * 16 + q * 4 + r;
        float acc = 0.f;
        if (m < NN) {
            const float* wr = Wl + (m * 64 + chan) * 32;
            #pragma unroll
            for (int j = 0; j < 32; ++j) acc += wr[j] * Wpred[j];
        }
        wcombP[o] = acc;
    } else if (gid == 56320) {
        float acc = bp[0];
        #pragma unroll
        for (int j = 0; j < 32; ++j) acc += bl[j] * Wpred[j];
        wcombP[4096] = acc;
    }
}

// ---------------------------------------------------------------------------
// One GAT layer for TWO graphs at once (R10: ILP x2 to cover latency).
// Per head h:
//   P[u] FIRST (independent of this head's GEMM -> its ~250cy LDS/exp/shfl
//   chain hides under the GEMM MFMAs), then per ct: shared-B GEMM chains for
//   both graphs interleaved, pack, agg MFMA immediately (short hf lifetime).
// slabw: per-wave LDS, [2 graphs][448 f32] = cnt[16][20] + alsd[2][4][16].
// ---------------------------------------------------------------------------
template<int KK, bool RELU>
__device__ __forceinline__ void gat_layer2(int lane,
    const bf16x8 (*a)[KK], const short* wpB,
    const float* __restrict__ bias, const float* slabw,
    f32x4 (*o)[4], unsigned (*po)[4][2])
{
    const int m = lane & 15, q = lane >> 4;
    f32x4 agg[2][4];
    #pragma unroll
    for (int u = 0; u < 2; ++u)
        #pragma unroll
        for (int ct = 0; ct < 4; ++ct) agg[u][ct] = f32x4{0.f, 0.f, 0.f, 0.f};

    #pragma unroll
    for (int h = 0; h < 4; ++h) {
        // ---- P frags for both graphs (cnt*exp(leaky(als+ald))/Z) ----
        bf16x4 P[2];
        #pragma unroll
        for (int u = 0; u < 2; ++u) {
            const float* cntf = slabw + u * 448;
            const float* alsd = cntf + 320;
            f32x4 alv = *(const f32x4*)(alsd + h * 16 + q * 4);
            float ad  = alsd[64 + h * 16 + m];
            f32x4 cv  = *(const f32x4*)(cntf + m * 20 + q * 4);
            float l0 = alv[0] + ad, l1 = alv[1] + ad, l2 = alv[2] + ad, l3 = alv[3] + ad;
            l0 = fmaxf(l0, 0.f) + 0.2f * fminf(l0, 0.f);
            l1 = fmaxf(l1, 0.f) + 0.2f * fminf(l1, 0.f);
            l2 = fmaxf(l2, 0.f) + 0.2f * fminf(l2, 0.f);
            l3 = fmaxf(l3, 0.f) + 0.2f * fminf(l3, 0.f);
            float v0 = __expf(l0) * cv[0], v1 = __expf(l1) * cv[1];
            float v2 = __expf(l2) * cv[2], v3 = __expf(l3) * cv[3];
            float s = v0 + v1 + v2 + v3;
            s += __shfl_xor(s, 16);
            s += __shfl_xor(s, 32);
            float inv = (s > 0.f) ? 0.25f / s : 0.f;
            P[u] = mk4(pack2bf(v0 * inv, v1 * inv), pack2bf(v2 * inv, v3 * inv));
        }

        // ---- GEMM (B shared across graphs) + immediate agg ----
        #pragma unroll
        for (int ct = 0; ct < 4; ++ct) {
            f32x4 c0 = f32x4{0.f, 0.f, 0.f, 0.f}, c1 = f32x4{0.f, 0.f, 0.f, 0.f};
            #pragma unroll
            for (int kk = 0; kk < KK; ++kk) {
                bf16x8 b = *(const bf16x8*)(wpB +
                    (((h * 4 + ct) * KK + kk) * 64 + lane) * 8);
                c0 = __builtin_amdgcn_mfma_f32_16x16x32_bf16(a[0][kk], b, c0, 0, 0, 0);
                c1 = __builtin_amdgcn_mfma_f32_16x16x32_bf16(a[1][kk], b, c1, 0, 0, 0);
            }
            agg[0][ct] = __builtin_amdgcn_mfma_f32_16x16x16bf16_1k(
                mk4(pack2bf(c0[0], c0[1]), pack2bf(c0[2], c0[3])), P[0], agg[0][ct], 0, 0, 0);
            agg[1][ct] = __builtin_amdgcn_mfma_f32_16x16x16bf16_1k(
                mk4(pack2bf(c1[0], c1[1]), pack2bf(c1[2], c1[3])), P[1], agg[1][ct], 0, 0, 0);
        }
    }

    // ---- epilogue: bias[chan = ct*16+q*4+r] (+relu); bb shared across u ----
    #pragma unroll
    for (int ct = 0; ct < 4; ++ct) {
        float4 bb = *(const float4*)(bias + ct * 16 + q * 4);
        #pragma unroll
        for (int u = 0; u < 2; ++u) {
            float o0 = agg[u][ct][0] + bb.x, o1 = agg[u][ct][1] + bb.y;
            float o2v = agg[u][ct][2] + bb.z, o3 = agg[u][ct][3] + bb.w;
            if (RELU) {
                o0 = fmaxf(o0, 0.f);  o1 = fmaxf(o1, 0.f);
                o2v = fmaxf(o2v, 0.f); o3 = fmaxf(o3, 0.f);
                if (m >= NN) { o0 = 0.f; o1 = 0.f; o2v = 0.f; o3 = 0.f; }
                po[u][ct][0] = pack2bf(o0, o1);
                po[u][ct][1] = pack2bf(o2v, o3);
            } else {
                o[u][ct] = f32x4{o0, o1, o2v, o3};
            }
        }
    }
}

// ---------------------------------------------------------------------------
// Persistent blocks: 1024 thr (16 waves), 1 block/CU, 4 graphs/wave processed
// as 2 PAIRS (two independent chains interleaved -> latency hiding; the kernel
// was latency-bound: VALU 30% + MFMA 15%, HBM 10%, 4 waves/SIMD).
// LDS: weights 104448 + 2-ctx slab 57344 = 161792 B (<= 160 KiB).
// (1024,4): 128-VGPR budget; prior VGPR=56, pairing expected ~110.
// ---------------------------------------------------------------------------
__global__ __launch_bounds__(1024, 4) void gat_fused(
    const float* __restrict__ feature,   // [B,14,128]
    const int*   __restrict__ edge_list, // [B,182,2] int32
    const float* __restrict__ b1, const float* __restrict__ b2,
    const short* __restrict__ wpck,      // wp1|wp2|battn1|battn2 (52224 shorts)
    const float* __restrict__ wcombP,    // [4097]
    float* __restrict__ out, int B)
{
    const int w = threadIdx.x >> 6, lane = threadIdx.x & 63;
    const int m = lane & 15, q = lane >> 4;

    __shared__ __align__(16) short    swts[52224];      // 104448 B: all weights
    __shared__ __align__(16) unsigned slab[16 * 896];   // 57344 B: 2 ctx per wave

    float* slabw = (float*)(slab + w * 896);            // [2][448]

    // ---- stage all packed weights into LDS (once; the only barrier) ----
    {
        const u32x4* srcw = (const u32x4*)wpck;
        u32x4* dstw = (u32x4*)swts;
        #pragma unroll
        for (int r = 0; r < 7; ++r) {
            int i = r * 1024 + (int)threadIdx.x;
            if (i < 6528) dstw[i] = srcw[i];
        }
    }
    __syncthreads();

    const short* swp1  = swts;
    const short* swp2  = swts + 32768;
    const short* sbat1 = swts + 49152;
    const short* sbat2 = swts + 51200;

    const int g0 = blockIdx.x * 64 + w * 4;

    #pragma clang loop unroll(disable)
    for (int it = 0; it < 2; ++it) {
        const int g = g0 + it * 2;
        if (g >= B) break;
        const bool act1 = (g + 1) < B;
        float* cnt0 = slabw;
        float* cnt1 = slabw + 448;

        // ---- S0: zero + scatter edges + self loops, both graphs ----
        #pragma unroll
        for (int i = 0; i < 5; ++i) {
            cnt0[i * 64 + lane] = 0.f;
            cnt1[i * 64 + lane] = 0.f;
        }
        {
            const int2* ep0 = (const int2*)edge_list + (size_t)g * EE;
            const int2* ep1 = ep0 + EE;
            #pragma unroll
            for (int r = 0; r < 3; ++r) {
                int i = r * 64 + lane;
                if (i < EE) {
                    int2 e0 = ep0[i];
                    atomicAdd(&cnt0[e0.y * 20 + e0.x], 1.f);
                    if (act1) { int2 e1 = ep1[i]; atomicAdd(&cnt1[e1.y * 20 + e1.x], 1.f); }
                }
            }
            if (lane < NN) {
                atomicAdd(&cnt0[lane * 21], 1.f);
                if (act1) atomicAdd(&cnt1[lane * 21], 1.f);
            }
        }

        // ---- S1: layer-1 A-fragments from global (f32 -> bf16), both ----
        bf16x8 a1[2][4];
        #pragma unroll
        for (int u = 0; u < 2; ++u)
            #pragma unroll
            for (int kk = 0; kk < 4; ++kk) a1[u][kk] = mk8(0, 0, 0, 0);
        if (m < NN) {
            const float* xg0 = feature + (size_t)g * (NN * 128) + m * 128;
            #pragma unroll
            for (int kk = 0; kk < 4; ++kk) {
                float4 v0 = *(const float4*)(xg0 + kk * 32 + q * 8);
                float4 v1 = *(const float4*)(xg0 + kk * 32 + q * 8 + 4);
                a1[0][kk] = mk8(pack2bf(v0.x, v0.y), pack2bf(v0.z, v0.w),
                                pack2bf(v1.x, v1.y), pack2bf(v1.z, v1.w));
            }
        }
        if (act1 && m < NN) {
            const float* xg1 = feature + (size_t)(g + 1) * (NN * 128) + m * 128;
            #pragma unroll
            for (int kk = 0; kk < 4; ++kk) {
                float4 v0 = *(const float4*)(xg1 + kk * 32 + q * 8);
                float4 v1 = *(const float4*)(xg1 + kk * 32 + q * 8 + 4);
                a1[1][kk] = mk8(pack2bf(v0.x, v0.y), pack2bf(v0.z, v0.w),
                                pack2bf(v1.x, v1.y), pack2bf(v1.z, v1.w));
            }
        }

        // ---- S2: attn1 via MFMA (B shared across graphs) -> alsd ----
        {
            f32x4 ca0 = f32x4{0.f, 0.f, 0.f, 0.f}, ca1 = f32x4{0.f, 0.f, 0.f, 0.f};
            #pragma unroll
            for (int kk = 0; kk < 4; ++kk) {
                bf16x8 b = *(const bf16x8*)(sbat1 + (kk * 64 + lane) * 8);
                ca0 = __builtin_amdgcn_mfma_f32_16x16x32_bf16(a1[0][kk], b, ca0, 0, 0, 0);
                ca1 = __builtin_amdgcn_mfma_f32_16x16x32_bf16(a1[1][kk], b, ca1, 0, 0, 0);
            }
            if (m < 8) {
                int off = (m >> 2) * 64 + (m & 3) * 16 + q * 4;
                *(f32x4*)(slabw + 320 + off) = ca0;
                *(f32x4*)(slabw + 448 + 320 + off) = ca1;
            }
        }

        // ---- S3: layer 1 (relu) -> po1 (bf16-packed chan rows) ----
        unsigned po1[2][4][2];
        gat_layer2<4, true>(lane, a1, swp1, b1, slabw, nullptr, po1);

        // ---- S4: layer2 A-frags: 16-bpermute transpose of po1, both ----
        bf16x8 a2[2][2];
        {
            int ad0 = ((q & 1) * 32 + m) * 4;
            int ad1_ = ad0 + 64;
            bool hi = (q >> 1) != 0;
            #pragma unroll
            for (int u = 0; u < 2; ++u)
            #pragma unroll
            for (int kk = 0; kk < 2; ++kk) {
                unsigned sA0 = __builtin_amdgcn_ds_bpermute(ad0, (int)po1[u][2 * kk][0]);
                unsigned sA1 = __builtin_amdgcn_ds_bpermute(ad0, (int)po1[u][2 * kk][1]);
                unsigned sB0 = __builtin_amdgcn_ds_bpermute(ad0, (int)po1[u][2 * kk + 1][0]);
                unsigned sB1 = __builtin_amdgcn_ds_bpermute(ad0, (int)po1[u][2 * kk + 1][1]);
                unsigned tA0 = __builtin_amdgcn_ds_bpermute(ad1_, (int)po1[u][2 * kk][0]);
                unsigned tA1 = __builtin_amdgcn_ds_bpermute(ad1_, (int)po1[u][2 * kk][1]);
                unsigned tB0 = __builtin_amdgcn_ds_bpermute(ad1_, (int)po1[u][2 * kk + 1][0]);
                unsigned tB1 = __builtin_amdgcn_ds_bpermute(ad1_, (int)po1[u][2 * kk + 1][1]);
                a2[u][kk] = mk8(hi ? sB0 : sA0, hi ? sB1 : sA1,
                                hi ? tB0 : tA0, hi ? tB1 : tA1);
            }
        }

        // ---- S5: attn2 -> alsd (overwrites layer-1 alsd), both ----
        {
            f32x4 ca0 = f32x4{0.f, 0.f, 0.f, 0.f}, ca1 = f32x4{0.f, 0.f, 0.f, 0.f};
            #pragma unroll
            for (int kk = 0; kk < 2; ++kk) {
                bf16x8 b = *(const bf16x8*)(sbat2 + (kk * 64 + lane) * 8);
                ca0 = __builtin_amdgcn_mfma_f32_16x16x32_bf16(a2[0][kk], b, ca0, 0, 0, 0);
                ca1 = __builtin_amdgcn_mfma_f32_16x16x32_bf16(a2[1][kk], b, ca1, 0, 0, 0);
            }
            if (m < 8) {
                int off = (m >> 2) * 64 + (m & 3) * 16 + q * 4;
                *(f32x4*)(slabw + 320 + off) = ca0;
                *(f32x4*)(slabw + 448 + 320 + off) = ca1;
            }
        }

        // ---- S6: layer 2 -> o2 (node = m lanes, chan = ct*16+q*4+r regs) ----
        f32x4 o2[2][4];
        gat_layer2<2, false>(lane, a2, swp2, b2, slabw, o2, nullptr);

        // ---- S7: head: p = sum o2 * wcombP (wv shared); 64-lane reduce x2 ----
        float p0 = 0.f, p1 = 0.f;
        #pragma unroll
        for (int ct = 0; ct < 4; ++ct) {
            float4 wv = *(const float4*)(wcombP + ((ct * 4 + q) * 16 + m) * 4);
            p0 += o2[0][ct][0] * wv.x + o2[0][ct][1] * wv.y +
                  o2[0][ct][2] * wv.z + o2[0][ct][3] * wv.w;
            p1 += o2[1][ct][0] * wv.x + o2[1][ct][1] * wv.y +
                  o2[1][ct][2] * wv.z + o2[1][ct][3] * wv.w;
        }
        p0 += __shfl_xor(p0, 1);  p1 += __shfl_xor(p1, 1);
        p0 += __shfl_xor(p0, 2);  p1 += __shfl_xor(p1, 2);
        p0 += __shfl_xor(p0, 4);  p1 += __shfl_xor(p1, 4);
        p0 += __shfl_xor(p0, 8);  p1 += __shfl_xor(p1, 8);
        p0 += __shfl_xor(p0, 16); p1 += __shfl_xor(p1, 16);
        p0 += __shfl_xor(p0, 32); p1 += __shfl_xor(p1, 32);
        if (lane == 0) {
            float cc = wcombP[4096];
            out[g] = 1.f / (1.f + __expf(-(p0 + cc)));
            if (act1) out[g + 1] = 1.f / (1.f + __expf(-(p1 + cc)));
        }
    }
}

extern "C" void kernel_launch(void* const* d_in, const int* in_sizes, int n_in,
                              void* d_out, int out_size, void* d_ws, size_t ws_size,
                              hipStream_t stream) {
    const float* feature = (const float*)d_in[0];
    const int*   edges   = (const int*)d_in[1];
    const float* W1  = (const float*)d_in[2];
    const float* as1 = (const float*)d_in[3];
    const float* ad1 = (const float*)d_in[4];
    const float* b1  = (const float*)d_in[5];
    const float* W2  = (const float*)d_in[6];
    const float* as2 = (const float*)d_in[7];
    const float* ad2 = (const float*)d_in[8];
    const float* b2  = (const float*)d_in[9];
    const float* Wl  = (const float*)d_in[10];
    const float* bl  = (const float*)d_in[11];
    const float* Wp  = (const float*)d_in[12];
    const float* bp  = (const float*)d_in[13];
    float* out = (float*)d_out;

    short* wp1    = (short*)d_ws;            // 32768 sh
    short* wp2    = wp1 + 32768;             // 16384 sh
    short* battn1 = wp2 + 16384;             // 2048 sh
    short* battn2 = battn1 + 2048;           // 1024 sh  (wp1..battn2 contiguous)
    float* wcombP = (float*)(battn2 + 1024); // 4097 f32

    prep_pack<<<221, 256, 0, stream>>>(W1, W2, Wl, Wp, bl, bp, as1, ad1, as2, ad2,
                                       wp1, wp2, battn1, battn2, wcombP);

    const int B = in_sizes[0] / (NN * 128);
    gat_fused<<<(B + 63) / 64, 1024, 0, stream>>>(feature, edges, b1, b2,
                                                  wp1, wcombP, out, B);
}